// Round 2
// baseline (99.713 us; speedup 1.0000x reference)
//
#include <hip/hip_runtime.h>

#define BINS 10
#define NTHREADS 256

// ---------------------------------------------------------------------------
// GHM loss, single fused pass.
//   out = (1/tot) * sum_b bin_w[b] * bceSum[b]
// R2: replace O(BINS) register predicate accumulation (VALU-bound, ~50
// ops/elem) with direct bin index + per-thread-private LDS histogram slots
// (s[bin][tid], stride-1 in tid -> 2-way bank aliasing = free).
// idx = min(9,(int)(g*10f)) verified == searchsorted(border,g,'right')-1 for
// all representable g in [0,1) including all border/pred(border) cases.
// ---------------------------------------------------------------------------

__device__ __forceinline__ float wave_reduce_add(float v) {
#pragma unroll
    for (int off = 32; off > 0; off >>= 1) v += __shfl_down(v, off, 64);
    return v;
}

__global__ __launch_bounds__(NTHREADS) void ghm_pass1(
    const float* __restrict__ pred, const int* __restrict__ target,
    float* __restrict__ g_sum,          // [BINS] bce sums
    unsigned int* __restrict__ g_cnt,   // [BINS] counts
    int n4, int n)
{
    __shared__ float s_cnt[BINS][NTHREADS];
    __shared__ float s_sum[BINS][NTHREADS];

    const int tid = threadIdx.x;
#pragma unroll
    for (int b = 0; b < BINS; ++b) { s_cnt[b][tid] = 0.f; s_sum[b][tid] = 0.f; }
    __syncthreads();

    const float4* __restrict__ p4 = reinterpret_cast<const float4*>(pred);
    const int4*   __restrict__ t4 = reinterpret_cast<const int4*>(target);

    const int gtid   = blockIdx.x * blockDim.x + tid;
    const int stride = gridDim.x * blockDim.x;

    for (int i = gtid; i < n4; i += stride) {
        const float4 xv = p4[i];
        const int4   tv = t4[i];
        const float xs[4] = {xv.x, xv.y, xv.z, xv.w};
        const int   ts[4] = {tv.x, tv.y, tv.z, tv.w};
#pragma unroll
        for (int j = 0; j < 4; ++j) {
            const float x    = xs[j];
            const bool  tpos = (ts[j] != 0);
            // E = exp(-|x|) in (0,1]
            const float E   = __expf(-fabsf(x));
            const float r   = 1.0f + E;
            const float inv = __builtin_amdgcn_rcpf(r);
            // g = |sigmoid(x) - t|: (x>=0)==(t==1) -> E/(1+E), else 1/(1+E)
            const bool  cond = ((x >= 0.0f) == tpos);
            const float g    = cond ? (E * inv) : inv;
            // bce = max(x,0) - x*t + log(1+exp(-|x|))
            const float bce = fmaxf(x, 0.0f) - (tpos ? x : 0.0f) + __logf(r);
            // bin index (verified exact vs searchsorted-right at all borders)
            int k = (int)(g * 10.0f);
            k = (k > BINS - 1) ? (BINS - 1) : k;

            s_cnt[k][tid] += 1.0f;   // <=64/thread: exact in f32
            s_sum[k][tid] += bce;
        }
    }

    // Scalar tail (N % 4); N=2^25 -> empty.
    if (gtid == 0) {
        for (int i = n4 * 4; i < n; ++i) {
            const float x    = pred[i];
            const bool  tpos = (target[i] != 0);
            const float E   = __expf(-fabsf(x));
            const float r   = 1.0f + E;
            const float inv = __builtin_amdgcn_rcpf(r);
            const bool  cond = ((x >= 0.0f) == tpos);
            const float g    = cond ? (E * inv) : inv;
            const float bce = fmaxf(x, 0.0f) - (tpos ? x : 0.0f) + __logf(r);
            int k = (int)(g * 10.0f);
            k = (k > BINS - 1) ? (BINS - 1) : k;
            s_cnt[k][tid] += 1.0f;
            s_sum[k][tid] += bce;
        }
    }
    __syncthreads();

    // Per-wave shuffle reduce of each thread's private column, then block
    // combine in LDS, then one global atomic per bin.
    __shared__ float r_sum[BINS];
    __shared__ float r_cnt[BINS];
    if (tid < BINS) { r_sum[tid] = 0.f; r_cnt[tid] = 0.f; }
    __syncthreads();

    const int lane = tid & 63;
#pragma unroll
    for (int b = 0; b < BINS; ++b) {
        const float v = wave_reduce_add(s_sum[b][tid]);
        const float c = wave_reduce_add(s_cnt[b][tid]);
        if (lane == 0) { atomicAdd(&r_sum[b], v); atomicAdd(&r_cnt[b], c); }
    }
    __syncthreads();

    if (tid < BINS) {
        atomicAdd(&g_sum[tid], r_sum[tid]);
        // block partial count <= 16384 -> exact in float
        atomicAdd(&g_cnt[tid], (unsigned int)(r_cnt[tid] + 0.5f));
    }
}

__global__ void ghm_finalize(const float* __restrict__ g_sum,
                             const unsigned int* __restrict__ g_cnt,
                             const float* __restrict__ acc_sum,
                             float* __restrict__ out, float tot)
{
    if (threadIdx.x == 0 && blockIdx.x == 0) {
        float binw[BINS];
        int n = 0;
#pragma unroll
        for (int b = 0; b < BINS; ++b) {
            const float c  = (float)g_cnt[b];
            const bool  ne = (c > 0.0f);
            const float accn = ne ? (0.9f * acc_sum[b] + 0.1f * c) : acc_sum[b];
            binw[b] = ne ? (tot / accn) : 0.0f;
            n += ne ? 1 : 0;
        }
        const float scale = (n > 0) ? (1.0f / (float)n) : 1.0f;
        float res = 0.0f;
#pragma unroll
        for (int b = 0; b < BINS; ++b) res += (binw[b] * scale) * g_sum[b];
        out[0] = res / tot;
    }
}

extern "C" void kernel_launch(void* const* d_in, const int* in_sizes, int n_in,
                              void* d_out, int out_size, void* d_ws, size_t ws_size,
                              hipStream_t stream) {
    const float* pred    = (const float*)d_in[0];
    const int*   target  = (const int*)d_in[1];
    const float* acc_sum = (const float*)d_in[2];
    float*       out     = (float*)d_out;

    const int n  = in_sizes[0];
    const int n4 = n / 4;

    float*        g_sum = (float*)d_ws;
    unsigned int* g_cnt = (unsigned int*)((float*)d_ws + BINS);

    // Accumulators must be zeroed every call (ws poisoned once, not re-poisoned).
    hipMemsetAsync(d_ws, 0, 2 * BINS * sizeof(float), stream);

    ghm_pass1<<<2048, NTHREADS, 0, stream>>>(pred, target, g_sum, g_cnt, n4, n);

    const float tot = (float)(n > 1 ? n : 1);
    ghm_finalize<<<1, 64, 0, stream>>>(g_sum, g_cnt, acc_sum, out, tot);
}